// Round 9
// baseline (1008.140 us; speedup 1.0000x reference)
//
#include <hip/hip_runtime.h>
#include <hip/hip_bf16.h>
#include <hip/hip_cooperative_groups.h>

namespace cg = cooperative_groups;

typedef __attribute__((ext_vector_type(8))) short short8;
typedef __attribute__((ext_vector_type(4))) float floatx4;
typedef unsigned int u32;

__device__ __forceinline__ u32 f2bf(float f) {
    union { float f; u32 u; } c; c.f = f;
    return (c.u + 0x7FFFu + ((c.u >> 16) & 1u)) >> 16;  // RNE
}

// ---- fp8 e4m3 helpers (HW cvt, gfx950 OCP; encode+decode use same HW) ----
__device__ __forceinline__ void fp8x8_acc(uint2 v, float* a) {
    auto f0 = __builtin_amdgcn_cvt_pk_f32_fp8((int)v.x, false);
    auto f1 = __builtin_amdgcn_cvt_pk_f32_fp8((int)v.x, true);
    auto f2 = __builtin_amdgcn_cvt_pk_f32_fp8((int)v.y, false);
    auto f3 = __builtin_amdgcn_cvt_pk_f32_fp8((int)v.y, true);
    a[0] += ((const float*)&f0)[0]; a[1] += ((const float*)&f0)[1];
    a[2] += ((const float*)&f1)[0]; a[3] += ((const float*)&f1)[1];
    a[4] += ((const float*)&f2)[0]; a[5] += ((const float*)&f2)[1];
    a[6] += ((const float*)&f3)[0]; a[7] += ((const float*)&f3)[1];
}
__device__ __forceinline__ void fp8x8_dec(uint2 v, float* x) {
    auto f0 = __builtin_amdgcn_cvt_pk_f32_fp8((int)v.x, false);
    auto f1 = __builtin_amdgcn_cvt_pk_f32_fp8((int)v.x, true);
    auto f2 = __builtin_amdgcn_cvt_pk_f32_fp8((int)v.y, false);
    auto f3 = __builtin_amdgcn_cvt_pk_f32_fp8((int)v.y, true);
    x[0] = ((const float*)&f0)[0]; x[1] = ((const float*)&f0)[1];
    x[2] = ((const float*)&f1)[0]; x[3] = ((const float*)&f1)[1];
    x[4] = ((const float*)&f2)[0]; x[5] = ((const float*)&f2)[1];
    x[6] = ((const float*)&f3)[0]; x[7] = ((const float*)&f3)[1];
}
__device__ __forceinline__ u32 f32x4_to_fp8(float a, float b, float c, float d) {
    u32 w = (u32)__builtin_amdgcn_cvt_pk_fp8_f32(a, b, 0, false);
    w = (u32)__builtin_amdgcn_cvt_pk_fp8_f32(c, d, (int)w, true);
    return w;
}

#define CCAP 264       // 256 staged cols + pad (clamped reads stay in-bounds)
#define CAPB 8192      // per-bucket scratch capacity (expected 4096 +- 64)
#define LCOL_CAP 8192  // build-phase LDS sort capacity (>= bucket max)
#define POOL_BYTES 37888  // max over phases: build = (512+256*3+8192)*4

struct P {
    const int* src; const int* dst;
    int* gcnt; u32* pairs;
    int* rowptr; float* dinv; int* col;
    const float* x;
    const float *W1, *W2, *W3, *Wp1, *Wp2;
    const float *b1, *b2, *b3, *g1, *be1, *g2, *be2, *bp1, *bp2;
    unsigned short *w1t, *w2t, *w3t, *wp1t, *wp2t;
    u32 *hw, *hb;
    float* out;
    int N, E, nb, bucketB, gb, fb;
};

// Quad-per-node gather: quad q (lanes q*16..q*16+15) owns node node0+q; lane s16
// holds feats 8*s16..8*s16+7 (uint2 = 8 fp8). One wave-load serves 4 edges.
// Cols staged to LDS once per wave, broadcast via same-address ds_read per quad.
__device__ __forceinline__ void gatherq(const uint2* __restrict__ hw64,
                                        const int* __restrict__ col,
                                        int* __restrict__ ldsc,  // this wave's [CCAP]
                                        int begq, int endq, int beg, int stagelen,
                                        int lane, int s16, float* __restrict__ acc) {
    for (int i = lane; i < stagelen; i += 64) ldsc[i] = col[beg + i];
    __syncthreads();  // all waves stage exactly once; orders ds_write->ds_read
    int dq = endq - begq;
    int offq = begq - beg;
    int send = min(endq, beg + stagelen);
    int sdq = max(0, send - begq);
    int mx = sdq;
    mx = max(mx, __shfl_xor(mx, 16));
    mx = max(mx, __shfl_xor(mx, 32));
    for (int jb = 0; jb < mx; jb += 8) {
        uint2 v[8];
#pragma unroll
        for (int j = 0; j < 8; ++j) {
            int jj = jb + j;
            int cj = ldsc[min(offq + jj, CCAP - 1)];  // clamp only hits when !act
            bool act = jj < sdq;
            uint2 tv; tv.x = 0u; tv.y = 0u;
            if (act) tv = hw64[(size_t)cj * 16 + s16];
            v[j] = tv;
        }
#pragma unroll
        for (int j = 0; j < 8; ++j) fp8x8_acc(v[j], acc);
    }
    // rare fallback: merged range exceeded staging cap
    for (int j = sdq; j < dq; ++j) {
        int cj = col[begq + j];
        uint2 tv = hw64[(size_t)cj * 16 + s16];
        fp8x8_acc(tv, acc);
    }
}

// ---------------- phase 1: bucket scatter + weight transpose ----------------
__device__ void dev_bucket_trans(const P& p, int ci, int t, char* pool) {
    if (ci >= p.bucketB) {
        int i = (ci - p.bucketB) * 256 + t;
        const float* in; unsigned short* out; int cols, li;
        if (i < 16384)      { in = p.W1;  out = p.w1t;  cols = 128; li = i; }
        else if (i < 32768) { in = p.W2;  out = p.w2t;  cols = 128; li = i - 16384; }
        else if (i < 49152) { in = p.W3;  out = p.w3t;  cols = 128; li = i - 32768; }
        else if (i < 65536) { in = p.Wp1; out = p.wp1t; cols = 128; li = i - 49152; }
        else                { in = p.Wp2; out = p.wp2t; cols = 64;  li = i - 65536; }
        int r = li / cols, c = li - r * cols;
        out[(size_t)c * 128 + r] = (unsigned short)f2bf(in[li]);
        return;
    }
    int* cnt   = (int*)pool;
    int* gbase = cnt + 512;
    int* cur   = gbase + 512;
    __syncthreads();  // LDS reuse guard (grid-stride safety)
    cnt[t] = 0; cnt[t + 256] = 0;
    __syncthreads();
    int e0 = ci * 8192;
    int ne = min(8192, p.E - e0);
    for (int i = t; i < ne; i += 256) atomicAdd(&cnt[p.dst[e0 + i] >> 8], 1);
    __syncthreads();
    for (int b = t; b < p.nb; b += 256) {
        int c = cnt[b];
        gbase[b] = c ? (b * CAPB + atomicAdd(&p.gcnt[b], c)) : 0;
        cur[b] = 0;
    }
    __syncthreads();
    for (int i = t; i < ne; i += 256) {
        int d = p.dst[e0 + i];
        int s = p.src[e0 + i];
        int b = d >> 8;
        int pp = atomicAdd(&cur[b], 1);
        p.pairs[gbase[b] + pp] = (u32)s | ((u32)(d & 255) << 24);
    }
}

// ---------------- phase 2: compact bucket scratch into final CSR ----------------
__device__ void dev_build(const P& p, int b, int t, char* pool) {
    int* pre  = (int*)pool;   // 512
    int* cnt  = pre + 512;    // 256
    int* incl = cnt + 256;    // 256
    int* cur  = incl + 256;   // 256
    int* lcol = cur + 256;    // 8192
    __syncthreads();  // LDS reuse guard
    pre[t] = (t < p.nb) ? p.gcnt[t] : 0;
    pre[t + 256] = (t + 256 < p.nb) ? p.gcnt[t + 256] : 0;
    __syncthreads();
    for (int off = 1; off < 512; off <<= 1) {
        int a0 = (t >= off) ? pre[t - off] : 0;
        int a1 = (t + 256 >= off) ? pre[t + 256 - off] : 0;
        __syncthreads();
        pre[t] += a0;
        pre[t + 256] += a1;
        __syncthreads();
    }
    int myg = p.gcnt[b];
    int base = pre[b] - myg;   // exclusive prefix = final CSR base for bucket b
    int sbase = b * CAPB;      // scratch base
    int ecnt = myg;
    cnt[t] = 0;
    __syncthreads();
    for (int j = t; j < ecnt; j += 256) atomicAdd(&cnt[p.pairs[sbase + j] >> 24], 1);
    __syncthreads();
    incl[t] = cnt[t];
    __syncthreads();
    for (int off = 1; off < 256; off <<= 1) {
        int a = (t >= off) ? incl[t - off] : 0;
        __syncthreads();
        incl[t] += a;
        __syncthreads();
    }
    int myc = cnt[t];
    int ex = incl[t] - myc;
    int node = b * 256 + t;
    if (node < p.N) {
        p.rowptr[node] = base + ex;
        p.dinv[node] = rsqrtf((float)myc + 1.0f);  // +1 self-loop
    }
    cur[t] = ex;
    if (b == 0 && t == 0) p.rowptr[p.N] = p.E;
    __syncthreads();
    if (ecnt <= LCOL_CAP) {
        for (int j = t; j < ecnt; j += 256) {
            u32 v = p.pairs[sbase + j];
            int r = atomicAdd(&cur[v >> 24], 1);
            lcol[r] = (int)(v & 0xFFFFFF);
        }
        __syncthreads();
        for (int j = t; j < ecnt; j += 256) p.col[base + j] = lcol[j];
    } else {
        for (int j = t; j < ecnt; j += 256) {
            u32 v = p.pairs[sbase + j];
            int r = atomicAdd(&cur[v >> 24], 1);
            p.col[base + r] = (int)(v & 0xFFFFFF);
        }
    }
}

// ---------------- phase 3: gemm1 (x f32 -> hw fp8, dinv-scaled) ----------------
__device__ void dev_gemm1(const P& p, int tile, int t, char* pool) {
    typedef unsigned short row132[132];
    row132* xs = (row132*)pool;  // 64 rows, 264B stride
    __syncthreads();  // LDS reuse guard
    int wave = t >> 6, lane = t & 63;
    int r0 = tile * 64;
    int M = p.N;
#pragma unroll
    for (int i = 0; i < 8; ++i) {
        int idx = i * 256 + t;
        int row = idx >> 5, c4 = idx & 31;
        int grow = r0 + row;
        float4 f = {0.f, 0.f, 0.f, 0.f};
        if (grow < M) f = ((const float4*)p.x)[(size_t)grow * 32 + c4];
        uint2 bb;
        bb.x = f2bf(f.x) | (f2bf(f.y) << 16);
        bb.y = f2bf(f.z) | (f2bf(f.w) << 16);
        *(uint2*)&xs[row][c4 * 4] = bb;
    }
    __syncthreads();
    int m0 = r0 + wave * 16;
    if (m0 >= M) return;
    int quad = lane >> 4, lr = lane & 15;
    int lrow = wave * 16 + lr;
    int row = m0 + lr;
    bool wr = row < M;
    short8 b0 = *(const short8*)&xs[lrow][quad * 8];
    short8 b1 = *(const short8*)&xs[lrow][32 + quad * 8];
    short8 b2 = *(const short8*)&xs[lrow][64 + quad * 8];
    short8 b3 = *(const short8*)&xs[lrow][96 + quad * 8];
    float di = wr ? p.dinv[row] : 0.f;
    const short* Wt = (const short*)p.w1t;
#pragma unroll
    for (int nt = 0; nt < 8; ++nt) {
        int ncol = nt * 16 + lr;
        const short8* Wp = (const short8*)(Wt + (size_t)ncol * 128 + quad * 8);
        short8 a0 = Wp[0], a1 = Wp[4], a2 = Wp[8], a3 = Wp[12];
        floatx4 acc = {0.f, 0.f, 0.f, 0.f};
        acc = __builtin_amdgcn_mfma_f32_16x16x32_bf16(a0, b0, acc, 0, 0, 0);
        acc = __builtin_amdgcn_mfma_f32_16x16x32_bf16(a1, b1, acc, 0, 0, 0);
        acc = __builtin_amdgcn_mfma_f32_16x16x32_bf16(a2, b2, acc, 0, 0, 0);
        acc = __builtin_amdgcn_mfma_f32_16x16x32_bf16(a3, b3, acc, 0, 0, 0);
        if (wr) {
            p.hw[(size_t)row * 32 + nt * 4 + quad] =
                f32x4_to_fp8(acc[0] * di, acc[1] * di, acc[2] * di, acc[3] * di);
        }
    }
}

// ---------------- phase 4/5: fused conv ----------------
__device__ void dev_fconv(const uint2* __restrict__ hw64,
                          const int* __restrict__ rowptr, const int* __restrict__ col,
                          const float* __restrict__ dinv, const float* __restrict__ bias,
                          const float* __restrict__ gam, const float* __restrict__ bet,
                          const short* __restrict__ Wt, u32* __restrict__ out,
                          int N, int tile, int t, char* pool) {
    typedef unsigned short row136[136];
    row136* rows = (row136*)pool;                      // 16 x 136 ushort = 4352B
    int (*ldsc)[CCAP] = (int(*)[CCAP])(pool + 4352);   // 4 x 264 int = 4224B
    __syncthreads();  // LDS reuse guard
    int wave = t >> 6, lane = t & 63;
    int q = lane >> 4, s16 = lane & 15;
    int nb0 = tile * 16;
    int node0 = nb0 + wave * 4;
    int node = node0 + q;
    bool ok = node < N;
    int beg = rowptr[min(node0, N)];
    int e4  = rowptr[min(node0 + 4, N)];
    int begq = rowptr[min(node, N)];
    int endq = ok ? rowptr[min(node + 1, N)] : begq;
    int stagelen = min(e4 - beg, 256);
    uint2 selfd; selfd.x = 0u; selfd.y = 0u;
    float di = 0.f;
    if (ok) {
        selfd = hw64[(size_t)node * 16 + s16];
        di = dinv[node];
    }
    float acc[8] = {0.f, 0.f, 0.f, 0.f, 0.f, 0.f, 0.f, 0.f};
    gatherq(hw64, col, ldsc[wave], begq, endq, beg, stagelen, lane, s16, acc);

    float sx[8]; fp8x8_dec(selfd, sx);
    float4 bv0 = *(const float4*)(bias + 8 * s16);
    float4 bv1 = *(const float4*)(bias + 8 * s16 + 4);
    float a[8];
    a[0] = fmaxf(di * (acc[0] + sx[0]) + bv0.x, 0.f);
    a[1] = fmaxf(di * (acc[1] + sx[1]) + bv0.y, 0.f);
    a[2] = fmaxf(di * (acc[2] + sx[2]) + bv0.z, 0.f);
    a[3] = fmaxf(di * (acc[3] + sx[3]) + bv0.w, 0.f);
    a[4] = fmaxf(di * (acc[4] + sx[4]) + bv1.x, 0.f);
    a[5] = fmaxf(di * (acc[5] + sx[5]) + bv1.y, 0.f);
    a[6] = fmaxf(di * (acc[6] + sx[6]) + bv1.z, 0.f);
    a[7] = fmaxf(di * (acc[7] + sx[7]) + bv1.w, 0.f);
    if (!ok) {
#pragma unroll
        for (int k = 0; k < 8; ++k) a[k] = 0.f;
    }
    float s = 0.f, qq = 0.f;
#pragma unroll
    for (int k = 0; k < 8; ++k) { s += a[k]; qq += a[k] * a[k]; }
#pragma unroll
    for (int mm = 8; mm >= 1; mm >>= 1) {
        s += __shfl_xor(s, mm);
        qq += __shfl_xor(qq, mm);
    }
    float mu = s * (1.f / 128.f);
    float var = qq * (1.f / 128.f) - mu * mu;
    float rs = rsqrtf(fmaxf(var, 0.f) + 1e-5f);
    float4 gv0 = *(const float4*)(gam + 8 * s16);
    float4 gv1 = *(const float4*)(gam + 8 * s16 + 4);
    float4 be0 = *(const float4*)(bet + 8 * s16);
    float4 be1 = *(const float4*)(bet + 8 * s16 + 4);
    a[0] = gv0.x * (a[0] - mu) * rs + be0.x;
    a[1] = gv0.y * (a[1] - mu) * rs + be0.y;
    a[2] = gv0.z * (a[2] - mu) * rs + be0.z;
    a[3] = gv0.w * (a[3] - mu) * rs + be0.w;
    a[4] = gv1.x * (a[4] - mu) * rs + be1.x;
    a[5] = gv1.y * (a[5] - mu) * rs + be1.y;
    a[6] = gv1.z * (a[6] - mu) * rs + be1.z;
    a[7] = gv1.w * (a[7] - mu) * rs + be1.w;
    if (!ok) {
#pragma unroll
        for (int k = 0; k < 8; ++k) a[k] = 0.f;
    }
    int r = wave * 4 + q;
    uint4 st;
    st.x = f2bf(a[0]) | (f2bf(a[1]) << 16);
    st.y = f2bf(a[2]) | (f2bf(a[3]) << 16);
    st.z = f2bf(a[4]) | (f2bf(a[5]) << 16);
    st.w = f2bf(a[6]) | (f2bf(a[7]) << 16);
    *(uint4*)((char*)&rows[r][0] + 16 * s16) = st;
    __syncthreads();

    int quad = lane >> 4, lr = lane & 15;
    short8 b0 = *(const short8*)&rows[lr][quad * 8];
    short8 b1 = *(const short8*)&rows[lr][32 + quad * 8];
    short8 b2 = *(const short8*)&rows[lr][64 + quad * 8];
    short8 b3 = *(const short8*)&rows[lr][96 + quad * 8];
    int onode = nb0 + lr;
    float di2 = (onode < N) ? dinv[onode] : 0.f;
#pragma unroll
    for (int k = 0; k < 2; ++k) {
        int ct = wave * 2 + k;
        int ncol = ct * 16 + lr;
        const short8* Wp = (const short8*)(Wt + (size_t)ncol * 128 + quad * 8);
        short8 a0 = Wp[0], a1 = Wp[4], a2 = Wp[8], a3 = Wp[12];
        floatx4 acm = {0.f, 0.f, 0.f, 0.f};
        acm = __builtin_amdgcn_mfma_f32_16x16x32_bf16(a0, b0, acm, 0, 0, 0);
        acm = __builtin_amdgcn_mfma_f32_16x16x32_bf16(a1, b1, acm, 0, 0, 0);
        acm = __builtin_amdgcn_mfma_f32_16x16x32_bf16(a2, b2, acm, 0, 0, 0);
        acm = __builtin_amdgcn_mfma_f32_16x16x32_bf16(a3, b3, acm, 0, 0, 0);
        int c0 = ct * 16 + quad * 4;
        if (onode < N) {
            out[(size_t)onode * 32 + (c0 >> 2)] =
                f32x4_to_fp8(acm[0] * di2, acm[1] * di2, acm[2] * di2, acm[3] * di2);
        }
    }
}

// ---------------- phase 6: fused head ----------------
__device__ void dev_fhead(const uint2* __restrict__ hw64,
                          const int* __restrict__ rowptr, const int* __restrict__ col,
                          const float* __restrict__ dinv, const float* __restrict__ bias,
                          const short* __restrict__ Wp1t, const float* __restrict__ bp1,
                          const short* __restrict__ Wp2t, const float* __restrict__ bp2,
                          float* __restrict__ out, int N, int tile, int t, char* pool) {
    typedef unsigned short row136[136];
    row136* rows = (row136*)pool;                      // 4352B
    row136* h1s  = (row136*)(pool + 4352);             // 4352B
    int (*ldsc)[CCAP] = (int(*)[CCAP])(pool + 8704);   // 4224B
    __syncthreads();  // LDS reuse guard
    int wave = t >> 6, lane = t & 63;
    int q = lane >> 4, s16 = lane & 15;
    int nb0 = tile * 16;
    int node0 = nb0 + wave * 4;
    int node = node0 + q;
    bool ok = node < N;
    int beg = rowptr[min(node0, N)];
    int e4  = rowptr[min(node0 + 4, N)];
    int begq = rowptr[min(node, N)];
    int endq = ok ? rowptr[min(node + 1, N)] : begq;
    int stagelen = min(e4 - beg, 256);
    uint2 selfd; selfd.x = 0u; selfd.y = 0u;
    float di = 0.f;
    if (ok) {
        selfd = hw64[(size_t)node * 16 + s16];
        di = dinv[node];
    }
    float acc[8] = {0.f, 0.f, 0.f, 0.f, 0.f, 0.f, 0.f, 0.f};
    gatherq(hw64, col, ldsc[wave], begq, endq, beg, stagelen, lane, s16, acc);

    float sx[8]; fp8x8_dec(selfd, sx);
    float4 bv0 = *(const float4*)(bias + 8 * s16);
    float4 bv1 = *(const float4*)(bias + 8 * s16 + 4);
    float a[8];
    a[0] = fmaxf(di * (acc[0] + sx[0]) + bv0.x, 0.f);
    a[1] = fmaxf(di * (acc[1] + sx[1]) + bv0.y, 0.f);
    a[2] = fmaxf(di * (acc[2] + sx[2]) + bv0.z, 0.f);
    a[3] = fmaxf(di * (acc[3] + sx[3]) + bv0.w, 0.f);
    a[4] = fmaxf(di * (acc[4] + sx[4]) + bv1.x, 0.f);
    a[5] = fmaxf(di * (acc[5] + sx[5]) + bv1.y, 0.f);
    a[6] = fmaxf(di * (acc[6] + sx[6]) + bv1.z, 0.f);
    a[7] = fmaxf(di * (acc[7] + sx[7]) + bv1.w, 0.f);
    if (!ok) {
#pragma unroll
        for (int k = 0; k < 8; ++k) a[k] = 0.f;
    }
    int r = wave * 4 + q;
    uint4 st;
    st.x = f2bf(a[0]) | (f2bf(a[1]) << 16);
    st.y = f2bf(a[2]) | (f2bf(a[3]) << 16);
    st.z = f2bf(a[4]) | (f2bf(a[5]) << 16);
    st.w = f2bf(a[6]) | (f2bf(a[7]) << 16);
    *(uint4*)((char*)&rows[r][0] + 16 * s16) = st;
    __syncthreads();

    int quad = lane >> 4, lr = lane & 15;
    {   // h1 = h @ Wp1 + bp1  (2 col-tiles per wave)
        short8 b0 = *(const short8*)&rows[lr][quad * 8];
        short8 b1 = *(const short8*)&rows[lr][32 + quad * 8];
        short8 b2 = *(const short8*)&rows[lr][64 + quad * 8];
        short8 b3 = *(const short8*)&rows[lr][96 + quad * 8];
#pragma unroll
        for (int k = 0; k < 2; ++k) {
            int ct = wave * 2 + k;
            int ncol = ct * 16 + lr;
            const short8* Wp = (const short8*)(Wp1t + (size_t)ncol * 128 + quad * 8);
            short8 a0 = Wp[0], a1 = Wp[4], a2 = Wp[8], a3 = Wp[12];
            floatx4 acm = {0.f, 0.f, 0.f, 0.f};
            acm = __builtin_amdgcn_mfma_f32_16x16x32_bf16(a0, b0, acm, 0, 0, 0);
            acm = __builtin_amdgcn_mfma_f32_16x16x32_bf16(a1, b1, acm, 0, 0, 0);
            acm = __builtin_amdgcn_mfma_f32_16x16x32_bf16(a2, b2, acm, 0, 0, 0);
            acm = __builtin_amdgcn_mfma_f32_16x16x32_bf16(a3, b3, acm, 0, 0, 0);
            int c0 = ct * 16 + quad * 4;
            float4 bv = *(const float4*)(bp1 + c0);
            uint2 stq;
            stq.x = f2bf(acm[0] + bv.x) | (f2bf(acm[1] + bv.y) << 16);
            stq.y = f2bf(acm[2] + bv.z) | (f2bf(acm[3] + bv.w) << 16);
            *(uint2*)&h1s[lr][c0] = stq;
        }
    }
    __syncthreads();
    {   // out = sigmoid(h1 @ Wp2 + bp2)
        short8 b0 = *(const short8*)&h1s[lr][quad * 8];
        short8 b1 = *(const short8*)&h1s[lr][32 + quad * 8];
        short8 b2 = *(const short8*)&h1s[lr][64 + quad * 8];
        short8 b3 = *(const short8*)&h1s[lr][96 + quad * 8];
        int ncol = wave * 16 + lr;
        const short8* Wp = (const short8*)(Wp2t + (size_t)ncol * 128 + quad * 8);
        short8 a0 = Wp[0], a1 = Wp[4], a2 = Wp[8], a3 = Wp[12];
        floatx4 acm = {0.f, 0.f, 0.f, 0.f};
        acm = __builtin_amdgcn_mfma_f32_16x16x32_bf16(a0, b0, acm, 0, 0, 0);
        acm = __builtin_amdgcn_mfma_f32_16x16x32_bf16(a1, b1, acm, 0, 0, 0);
        acm = __builtin_amdgcn_mfma_f32_16x16x32_bf16(a2, b2, acm, 0, 0, 0);
        acm = __builtin_amdgcn_mfma_f32_16x16x32_bf16(a3, b3, acm, 0, 0, 0);
        int c0 = wave * 16 + quad * 4;
        int onode = nb0 + lr;
        if (onode < N) {
            float4 bv = *(const float4*)(bp2 + c0);
            float4 sg;
            sg.x = 1.f / (1.f + __expf(-(acm[0] + bv.x)));
            sg.y = 1.f / (1.f + __expf(-(acm[1] + bv.y)));
            sg.z = 1.f / (1.f + __expf(-(acm[2] + bv.z)));
            sg.w = 1.f / (1.f + __expf(-(acm[3] + bv.w)));
            *(float4*)(out + (size_t)onode * 64 + c0) = sg;
        }
    }
}

// ---------------- single cooperative mega-kernel ----------------
__global__ __launch_bounds__(256, 4) void mega_k(P p) {
    extern __shared__ __align__(16) char smem[];
    cg::grid_group g = cg::this_grid();
    int t = threadIdx.x;
    for (int i = blockIdx.x * 256 + t; i < 512; i += gridDim.x * 256) p.gcnt[i] = 0;
    __threadfence();
    g.sync();
    for (int c = blockIdx.x; c < p.bucketB + 288; c += gridDim.x)
        dev_bucket_trans(p, c, t, smem);
    __threadfence();
    g.sync();
    for (int b = blockIdx.x; b < p.nb; b += gridDim.x)
        dev_build(p, b, t, smem);
    __threadfence();
    g.sync();
    for (int tb = blockIdx.x; tb < p.gb; tb += gridDim.x)
        dev_gemm1(p, tb, t, smem);
    __threadfence();
    g.sync();
    for (int tb = blockIdx.x; tb < p.fb; tb += gridDim.x)
        dev_fconv((const uint2*)p.hw, p.rowptr, p.col, p.dinv, p.b1, p.g1, p.be1,
                  (const short*)p.w2t, p.hb, p.N, tb, t, smem);
    __threadfence();
    g.sync();
    for (int tb = blockIdx.x; tb < p.fb; tb += gridDim.x)
        dev_fconv((const uint2*)p.hb, p.rowptr, p.col, p.dinv, p.b2, p.g2, p.be2,
                  (const short*)p.w3t, p.hw, p.N, tb, t, smem);
    __threadfence();
    g.sync();
    for (int tb = blockIdx.x; tb < p.fb; tb += gridDim.x)
        dev_fhead((const uint2*)p.hw, p.rowptr, p.col, p.dinv, p.b3,
                  (const short*)p.wp1t, p.bp1, (const short*)p.wp2t, p.bp2,
                  p.out, p.N, tb, t, smem);
}

// ---------------- non-cooperative fallback wrappers ----------------
__global__ __launch_bounds__(256) void bucket_trans_k(P p) {
    extern __shared__ __align__(16) char smem[];
    dev_bucket_trans(p, blockIdx.x, threadIdx.x, smem);
}
__global__ __launch_bounds__(256) void build_k(P p) {
    extern __shared__ __align__(16) char smem[];
    dev_build(p, blockIdx.x, threadIdx.x, smem);
}
__global__ __launch_bounds__(256) void gemm1_k(P p) {
    extern __shared__ __align__(16) char smem[];
    dev_gemm1(p, blockIdx.x, threadIdx.x, smem);
}
__global__ __launch_bounds__(256) void fconv1_k(P p) {
    extern __shared__ __align__(16) char smem[];
    dev_fconv((const uint2*)p.hw, p.rowptr, p.col, p.dinv, p.b1, p.g1, p.be1,
              (const short*)p.w2t, p.hb, p.N, blockIdx.x, threadIdx.x, smem);
}
__global__ __launch_bounds__(256) void fconv2_k(P p) {
    extern __shared__ __align__(16) char smem[];
    dev_fconv((const uint2*)p.hb, p.rowptr, p.col, p.dinv, p.b2, p.g2, p.be2,
              (const short*)p.w3t, p.hw, p.N, blockIdx.x, threadIdx.x, smem);
}
__global__ __launch_bounds__(256) void fhead_k(P p) {
    extern __shared__ __align__(16) char smem[];
    dev_fhead((const uint2*)p.hw, p.rowptr, p.col, p.dinv, p.b3,
              (const short*)p.wp1t, p.bp1, (const short*)p.wp2t, p.bp2,
              p.out, p.N, blockIdx.x, threadIdx.x, smem);
}

extern "C" void kernel_launch(void* const* d_in, const int* in_sizes, int n_in,
                              void* d_out, int out_size, void* d_ws, size_t ws_size,
                              hipStream_t stream) {
    const int N = in_sizes[0] / 128;
    const int E = in_sizes[1] / 2;
    const int nb = (N + 255) >> 8;
    const int* edge = (const int*)d_in[1];

    char* ws = (char*)d_ws;
    size_t off = 0;
    auto alloc = [&](size_t b) -> char* {
        char* p = ws + off;
        off += (b + 255) & ~(size_t)255;
        return p;
    };
    P p;
    p.src = edge;
    p.dst = edge + E;
    p.x   = (const float*)d_in[0];
    p.W1  = (const float*)d_in[2];  p.b1  = (const float*)d_in[3];
    p.W2  = (const float*)d_in[4];  p.b2  = (const float*)d_in[5];
    p.W3  = (const float*)d_in[6];  p.b3  = (const float*)d_in[7];
    p.g1  = (const float*)d_in[8];  p.be1 = (const float*)d_in[9];
    p.g2  = (const float*)d_in[10]; p.be2 = (const float*)d_in[11];
    p.Wp1 = (const float*)d_in[12]; p.bp1 = (const float*)d_in[13];
    p.Wp2 = (const float*)d_in[14]; p.bp2 = (const float*)d_in[15];
    p.gcnt   = (int*)alloc(512 * 4);
    p.rowptr = (int*)alloc((size_t)(N + 1) * 4);
    p.dinv   = (float*)alloc((size_t)N * 4);
    p.pairs  = (u32*)alloc((size_t)nb * CAPB * 4);
    p.col    = (int*)alloc((size_t)E * 4);
    p.hw     = (u32*)alloc((size_t)N * 128);
    p.hb     = (u32*)alloc((size_t)N * 128);
    p.w1t  = (unsigned short*)alloc(128 * 128 * 2);
    p.w2t  = (unsigned short*)alloc(128 * 128 * 2);
    p.w3t  = (unsigned short*)alloc(128 * 128 * 2);
    p.wp1t = (unsigned short*)alloc(128 * 128 * 2);
    p.wp2t = (unsigned short*)alloc(64 * 128 * 2);
    p.out = (float*)d_out;
    p.N = N; p.E = E; p.nb = nb;
    p.bucketB = (E + 8191) / 8192;
    p.gb = (N + 63) / 64;
    p.fb = (N + 15) / 16;
    if (off > ws_size) return;

    static int s_grid = -1;
    if (s_grid < 0) {
        hipDeviceProp_t prop{};
        if (hipGetDeviceProperties(&prop, 0) == hipSuccess && prop.cooperativeLaunch) {
            int mb = 0;
            if (hipOccupancyMaxActiveBlocksPerMultiprocessor(&mb, mega_k, 256,
                                                             (size_t)POOL_BYTES) != hipSuccess ||
                mb < 1)
                mb = 4;
            if (mb > 8) mb = 8;
            s_grid = mb * prop.multiProcessorCount;
        } else {
            s_grid = 0;
        }
    }

    if (s_grid > 0) {
        void* args[] = {(void*)&p};
        hipLaunchCooperativeKernel((const void*)mega_k, dim3(s_grid), dim3(256),
                                   args, POOL_BYTES, stream);
        return;
    }

    // fallback: separate launches (identical numerics)
    hipMemsetAsync(p.gcnt, 0, 512 * 4, stream);
    bucket_trans_k<<<p.bucketB + 288, 256, 6144, stream>>>(p);
    build_k<<<p.nb, 256, POOL_BYTES, stream>>>(p);
    gemm1_k<<<p.gb, 256, 16896, stream>>>(p);
    fconv1_k<<<p.fb, 256, 8576, stream>>>(p);
    fconv2_k<<<p.fb, 256, 8576, stream>>>(p);
    fhead_k<<<p.fb, 256, 12928, stream>>>(p);
}

// Round 10
// 360.751 us; speedup vs baseline: 2.7946x; 2.7946x over previous
//
#include <hip/hip_runtime.h>
#include <hip/hip_bf16.h>

typedef __attribute__((ext_vector_type(8))) short short8;
typedef __attribute__((ext_vector_type(4))) float floatx4;
typedef unsigned int u32;

__device__ __forceinline__ u32 f2bf(float f) {
    union { float f; u32 u; } c; c.f = f;
    return (c.u + 0x7FFFu + ((c.u >> 16) & 1u)) >> 16;  // RNE
}

// ---- fp8 e4m3 helpers (HW cvt, gfx950 OCP; encode+decode use same HW) ----
__device__ __forceinline__ void fp8x8_acc(uint2 v, float* a) {
    auto f0 = __builtin_amdgcn_cvt_pk_f32_fp8((int)v.x, false);
    auto f1 = __builtin_amdgcn_cvt_pk_f32_fp8((int)v.x, true);
    auto f2 = __builtin_amdgcn_cvt_pk_f32_fp8((int)v.y, false);
    auto f3 = __builtin_amdgcn_cvt_pk_f32_fp8((int)v.y, true);
    a[0] += ((const float*)&f0)[0]; a[1] += ((const float*)&f0)[1];
    a[2] += ((const float*)&f1)[0]; a[3] += ((const float*)&f1)[1];
    a[4] += ((const float*)&f2)[0]; a[5] += ((const float*)&f2)[1];
    a[6] += ((const float*)&f3)[0]; a[7] += ((const float*)&f3)[1];
}
__device__ __forceinline__ void fp8x8_dec(uint2 v, float* x) {
    auto f0 = __builtin_amdgcn_cvt_pk_f32_fp8((int)v.x, false);
    auto f1 = __builtin_amdgcn_cvt_pk_f32_fp8((int)v.x, true);
    auto f2 = __builtin_amdgcn_cvt_pk_f32_fp8((int)v.y, false);
    auto f3 = __builtin_amdgcn_cvt_pk_f32_fp8((int)v.y, true);
    x[0] = ((const float*)&f0)[0]; x[1] = ((const float*)&f0)[1];
    x[2] = ((const float*)&f1)[0]; x[3] = ((const float*)&f1)[1];
    x[4] = ((const float*)&f2)[0]; x[5] = ((const float*)&f2)[1];
    x[6] = ((const float*)&f3)[0]; x[7] = ((const float*)&f3)[1];
}
__device__ __forceinline__ u32 f32x4_to_fp8(float a, float b, float c, float d) {
    u32 w = (u32)__builtin_amdgcn_cvt_pk_fp8_f32(a, b, 0, false);
    w = (u32)__builtin_amdgcn_cvt_pk_fp8_f32(c, d, (int)w, true);
    return w;
}

#define CCAP 264   // 256 staged cols + pad (clamped reads stay in-bounds)
#define CAPB 8192  // per-bucket scratch capacity (expected 4096 +- 64)

// Quad-per-node gather: quad q (lanes q*16..q*16+15) owns node node0+q; lane s16
// holds feats 8*s16..8*s16+7 (uint2 = 8 fp8). One wave-load serves 4 edges.
// Cols staged to LDS once per wave, broadcast via same-address ds_read per quad.
__device__ __forceinline__ void gatherq(const uint2* __restrict__ hw64,
                                        const int* __restrict__ col,
                                        int* __restrict__ ldsc,  // this wave's [CCAP]
                                        int begq, int endq, int beg, int stagelen,
                                        int lane, int s16, float* __restrict__ acc) {
    for (int i = lane; i < stagelen; i += 64) ldsc[i] = col[beg + i];
    __syncthreads();  // all waves stage exactly once; orders ds_write->ds_read
    int dq = endq - begq;
    int offq = begq - beg;
    int send = min(endq, beg + stagelen);
    int sdq = max(0, send - begq);
    int mx = sdq;
    mx = max(mx, __shfl_xor(mx, 16));
    mx = max(mx, __shfl_xor(mx, 32));
    for (int jb = 0; jb < mx; jb += 8) {
        uint2 v[8];
#pragma unroll
        for (int j = 0; j < 8; ++j) {
            int jj = jb + j;
            int cj = ldsc[min(offq + jj, CCAP - 1)];  // clamp only hits when !act
            bool act = jj < sdq;
            uint2 tv; tv.x = 0u; tv.y = 0u;
            if (act) tv = hw64[(size_t)cj * 16 + s16];
            v[j] = tv;
        }
#pragma unroll
        for (int j = 0; j < 8; ++j) fp8x8_acc(v[j], acc);
    }
    // rare fallback: merged range exceeded staging cap
    for (int j = sdq; j < dq; ++j) {
        int cj = col[begq + j];
        uint2 tv = hw64[(size_t)cj * 16 + s16];
        fp8x8_acc(tv, acc);
    }
}

// ---------------- CSR build (fixed-capacity buckets, no hist pass) ----------------
// One edge pass: per block LDS-count -> one global atomicAdd per bucket reserving a
// contiguous range in the bucket's private region [b*CAPB, (b+1)*CAPB) -> LDS-cursor
// scatter of (src | (dst&255)<<24). Weight transpose piggybacks on tail blocks.
__global__ __launch_bounds__(256) void bucket_trans_k(
        const int* __restrict__ src, const int* __restrict__ dst,
        int* __restrict__ gcnt, u32* __restrict__ pairs, int E, int nb, int bucketB,
        const float* __restrict__ W1, const float* __restrict__ W2,
        const float* __restrict__ W3, const float* __restrict__ Wp1,
        const float* __restrict__ Wp2,
        unsigned short* __restrict__ o1, unsigned short* __restrict__ o2,
        unsigned short* __restrict__ o3, unsigned short* __restrict__ o4,
        unsigned short* __restrict__ o5) {
    int t = threadIdx.x;
    if ((int)blockIdx.x >= bucketB) {
        int i = (blockIdx.x - bucketB) * 256 + t;
        const float* in; unsigned short* out; int cols, li;
        if (i < 16384)      { in = W1;  out = o1; cols = 128; li = i; }
        else if (i < 32768) { in = W2;  out = o2; cols = 128; li = i - 16384; }
        else if (i < 49152) { in = W3;  out = o3; cols = 128; li = i - 32768; }
        else if (i < 65536) { in = Wp1; out = o4; cols = 128; li = i - 49152; }
        else                { in = Wp2; out = o5; cols = 64;  li = i - 65536; }
        int r = li / cols, c = li - r * cols;
        out[(size_t)c * 128 + r] = (unsigned short)f2bf(in[li]);
        return;
    }
    __shared__ int cnt[512];
    __shared__ int gbase[512];
    __shared__ int cur[512];
    cnt[t] = 0; cnt[t + 256] = 0;
    __syncthreads();
    int e0 = blockIdx.x * 8192;
    int ne = min(8192, E - e0);
    for (int i = t; i < ne; i += 256) atomicAdd(&cnt[dst[e0 + i] >> 8], 1);
    __syncthreads();
    for (int b = t; b < nb; b += 256) {
        int c = cnt[b];
        gbase[b] = c ? (b * CAPB + atomicAdd(&gcnt[b], c)) : 0;
        cur[b] = 0;
    }
    __syncthreads();
    for (int i = t; i < ne; i += 256) {
        int d = dst[e0 + i];
        int s = src[e0 + i];
        int b = d >> 8;
        int p = atomicAdd(&cur[b], 1);
        pairs[gbase[b] + p] = (u32)s | ((u32)(d & 255) << 24);
    }
}

#define LCOL_CAP 12288
// Compact bucket b's scratch region into final CSR. The exclusive bucket prefix is
// computed in-kernel (512-entry Hillis-Steele over gcnt, ~2KB LDS) - no bscan launch.
__global__ __launch_bounds__(256) void build_k(const u32* __restrict__ pairs,
                                               const int* __restrict__ gcnt,
                                               int* __restrict__ rowptr,
                                               float* __restrict__ dinv,
                                               int* __restrict__ col,
                                               int N, int E, int nb) {
    __shared__ int pre[512];
    __shared__ int cnt[256], incl[256], cur[256];
    __shared__ int lcol[LCOL_CAP];
    int b = blockIdx.x, t = threadIdx.x;
    pre[t] = (t < nb) ? gcnt[t] : 0;
    pre[t + 256] = (t + 256 < nb) ? gcnt[t + 256] : 0;
    __syncthreads();
    for (int off = 1; off < 512; off <<= 1) {
        int a0 = (t >= off) ? pre[t - off] : 0;
        int a1 = (t + 256 >= off) ? pre[t + 256 - off] : 0;
        __syncthreads();
        pre[t] += a0;
        pre[t + 256] += a1;
        __syncthreads();
    }
    int myg = gcnt[b];
    int base = pre[b] - myg;   // exclusive prefix = final CSR base for bucket b
    int sbase = b * CAPB;      // scratch base
    int ecnt = myg;
    cnt[t] = 0;
    __syncthreads();
    for (int j = t; j < ecnt; j += 256) atomicAdd(&cnt[pairs[sbase + j] >> 24], 1);
    __syncthreads();
    incl[t] = cnt[t];
    __syncthreads();
    for (int off = 1; off < 256; off <<= 1) {
        int a = (t >= off) ? incl[t - off] : 0;
        __syncthreads();
        incl[t] += a;
        __syncthreads();
    }
    int myc = cnt[t];
    int ex = incl[t] - myc;
    int node = b * 256 + t;
    if (node < N) {
        rowptr[node] = base + ex;
        dinv[node] = rsqrtf((float)myc + 1.0f);  // +1 self-loop
    }
    cur[t] = ex;
    if (b == 0 && t == 0) rowptr[N] = E;
    __syncthreads();
    if (ecnt <= LCOL_CAP) {
        for (int j = t; j < ecnt; j += 256) {
            u32 v = pairs[sbase + j];
            int r = atomicAdd(&cur[v >> 24], 1);
            lcol[r] = (int)(v & 0xFFFFFF);
        }
        __syncthreads();
        for (int j = t; j < ecnt; j += 256) col[base + j] = lcol[j];
    } else {
        for (int j = t; j < ecnt; j += 256) {
            u32 v = pairs[sbase + j];
            int r = atomicAdd(&cur[v >> 24], 1);
            col[base + r] = (int)(v & 0xFFFFFF);
        }
    }
}

// ---------------- GEMM (layer 1: x f32 -> hw fp8, dinv-scaled) ----------------
// Coalesced float4 staging of the 64x128 f32 tile -> bf16 LDS (padded stride),
// MFMA fragments read from LDS.
__global__ __launch_bounds__(256) void gemm1_k(const float* __restrict__ A,
                                               const short* __restrict__ Wt,
                                               const float* __restrict__ dinv,
                                               u32* __restrict__ out, int M) {
    __shared__ unsigned short xs[64][132];  // bf16 tile, 264B row stride (2-way banks)
    int t = threadIdx.x;
    int wave = t >> 6, lane = t & 63;
    int r0 = blockIdx.x * 64;
#pragma unroll
    for (int i = 0; i < 8; ++i) {
        int idx = i * 256 + t;   // float4 index within 64x128 tile (32 per row)
        int row = idx >> 5;
        int c4 = idx & 31;
        int grow = r0 + row;
        float4 f = {0.f, 0.f, 0.f, 0.f};
        if (grow < M) f = ((const float4*)A)[(size_t)grow * 32 + c4];
        uint2 bb;
        bb.x = f2bf(f.x) | (f2bf(f.y) << 16);
        bb.y = f2bf(f.z) | (f2bf(f.w) << 16);
        *(uint2*)&xs[row][c4 * 4] = bb;
    }
    __syncthreads();
    int m0 = r0 + wave * 16;
    if (m0 >= M) return;
    int quad = lane >> 4, lr = lane & 15;
    int lrow = wave * 16 + lr;
    int row = m0 + lr;
    bool wr = row < M;
    short8 b0 = *(const short8*)&xs[lrow][quad * 8];
    short8 b1 = *(const short8*)&xs[lrow][32 + quad * 8];
    short8 b2 = *(const short8*)&xs[lrow][64 + quad * 8];
    short8 b3 = *(const short8*)&xs[lrow][96 + quad * 8];
    float di = wr ? dinv[row] : 0.f;
#pragma unroll
    for (int nt = 0; nt < 8; ++nt) {
        int ncol = nt * 16 + lr;
        const short8* Wp = (const short8*)(Wt + (size_t)ncol * 128 + quad * 8);
        short8 a0 = Wp[0], a1 = Wp[4], a2 = Wp[8], a3 = Wp[12];
        floatx4 acc = {0.f, 0.f, 0.f, 0.f};
        acc = __builtin_amdgcn_mfma_f32_16x16x32_bf16(a0, b0, acc, 0, 0, 0);
        acc = __builtin_amdgcn_mfma_f32_16x16x32_bf16(a1, b1, acc, 0, 0, 0);
        acc = __builtin_amdgcn_mfma_f32_16x16x32_bf16(a2, b2, acc, 0, 0, 0);
        acc = __builtin_amdgcn_mfma_f32_16x16x32_bf16(a3, b3, acc, 0, 0, 0);
        if (wr) {
            out[(size_t)row * 32 + nt * 4 + quad] =
                f32x4_to_fp8(acc[0] * di, acc[1] * di, acc[2] * di, acc[3] * di);
        }
    }
}

// ---------------- fused conv: agg(fp8 quad) + bias + relu + LN + @Wnext*dinv -> fp8 ----------------
__global__ __launch_bounds__(256) void fconv_k(const uint2* __restrict__ hw64,
                                               const int* __restrict__ rowptr,
                                               const int* __restrict__ col,
                                               const float* __restrict__ dinv,
                                               const float* __restrict__ bias,
                                               const float* __restrict__ gam,
                                               const float* __restrict__ bet,
                                               const short* __restrict__ Wt,
                                               u32* __restrict__ out, int N) {
    __shared__ unsigned short rows[16][136];
    __shared__ int ldsc[4][CCAP];
    int t = threadIdx.x, wave = t >> 6, lane = t & 63;
    int q = lane >> 4, s16 = lane & 15;
    int nb0 = blockIdx.x * 16;
    int node0 = nb0 + wave * 4;
    int node = node0 + q;
    bool ok = node < N;
    int beg = rowptr[min(node0, N)];
    int e4  = rowptr[min(node0 + 4, N)];
    int begq = rowptr[min(node, N)];
    int endq = ok ? rowptr[min(node + 1, N)] : begq;
    int stagelen = min(e4 - beg, 256);
    uint2 selfd; selfd.x = 0u; selfd.y = 0u;
    float di = 0.f;
    if (ok) {
        selfd = hw64[(size_t)node * 16 + s16];
        di = dinv[node];
    }
    float acc[8] = {0.f, 0.f, 0.f, 0.f, 0.f, 0.f, 0.f, 0.f};
    gatherq(hw64, col, ldsc[wave], begq, endq, beg, stagelen, lane, s16, acc);

    float sx[8]; fp8x8_dec(selfd, sx);
    float4 bv0 = *(const float4*)(bias + 8 * s16);
    float4 bv1 = *(const float4*)(bias + 8 * s16 + 4);
    float a[8];
    a[0] = fmaxf(di * (acc[0] + sx[0]) + bv0.x, 0.f);
    a[1] = fmaxf(di * (acc[1] + sx[1]) + bv0.y, 0.f);
    a[2] = fmaxf(di * (acc[2] + sx[2]) + bv0.z, 0.f);
    a[3] = fmaxf(di * (acc[3] + sx[3]) + bv0.w, 0.f);
    a[4] = fmaxf(di * (acc[4] + sx[4]) + bv1.x, 0.f);
    a[5] = fmaxf(di * (acc[5] + sx[5]) + bv1.y, 0.f);
    a[6] = fmaxf(di * (acc[6] + sx[6]) + bv1.z, 0.f);
    a[7] = fmaxf(di * (acc[7] + sx[7]) + bv1.w, 0.f);
    if (!ok) {
#pragma unroll
        for (int k = 0; k < 8; ++k) a[k] = 0.f;
    }
    float s = 0.f, qq = 0.f;
#pragma unroll
    for (int k = 0; k < 8; ++k) { s += a[k]; qq += a[k] * a[k]; }
#pragma unroll
    for (int mm = 8; mm >= 1; mm >>= 1) {
        s += __shfl_xor(s, mm);
        qq += __shfl_xor(qq, mm);
    }
    float mu = s * (1.f / 128.f);
    float var = qq * (1.f / 128.f) - mu * mu;
    float rs = rsqrtf(fmaxf(var, 0.f) + 1e-5f);
    float4 gv0 = *(const float4*)(gam + 8 * s16);
    float4 gv1 = *(const float4*)(gam + 8 * s16 + 4);
    float4 be0 = *(const float4*)(bet + 8 * s16);
    float4 be1 = *(const float4*)(bet + 8 * s16 + 4);
    a[0] = gv0.x * (a[0] - mu) * rs + be0.x;
    a[1] = gv0.y * (a[1] - mu) * rs + be0.y;
    a[2] = gv0.z * (a[2] - mu) * rs + be0.z;
    a[3] = gv0.w * (a[3] - mu) * rs + be0.w;
    a[4] = gv1.x * (a[4] - mu) * rs + be1.x;
    a[5] = gv1.y * (a[5] - mu) * rs + be1.y;
    a[6] = gv1.z * (a[6] - mu) * rs + be1.z;
    a[7] = gv1.w * (a[7] - mu) * rs + be1.w;
    if (!ok) {
#pragma unroll
        for (int k = 0; k < 8; ++k) a[k] = 0.f;
    }
    int r = wave * 4 + q;
    uint4 st;
    st.x = f2bf(a[0]) | (f2bf(a[1]) << 16);
    st.y = f2bf(a[2]) | (f2bf(a[3]) << 16);
    st.z = f2bf(a[4]) | (f2bf(a[5]) << 16);
    st.w = f2bf(a[6]) | (f2bf(a[7]) << 16);
    *(uint4*)((char*)&rows[r][0] + 16 * s16) = st;
    __syncthreads();

    int quad = lane >> 4, lr = lane & 15;
    short8 b0 = *(const short8*)&rows[lr][quad * 8];
    short8 b1 = *(const short8*)&rows[lr][32 + quad * 8];
    short8 b2 = *(const short8*)&rows[lr][64 + quad * 8];
    short8 b3 = *(const short8*)&rows[lr][96 + quad * 8];
    int onode = nb0 + lr;
    float di2 = (onode < N) ? dinv[onode] : 0.f;
#pragma unroll
    for (int k = 0; k < 2; ++k) {
        int ct = wave * 2 + k;
        int ncol = ct * 16 + lr;
        const short8* Wp = (const short8*)(Wt + (size_t)ncol * 128 + quad * 8);
        short8 a0 = Wp[0], a1 = Wp[4], a2 = Wp[8], a3 = Wp[12];
        floatx4 acm = {0.f, 0.f, 0.f, 0.f};
        acm = __builtin_amdgcn_mfma_f32_16x16x32_bf16(a0, b0, acm, 0, 0, 0);
        acm = __builtin_amdgcn_mfma_f32_16x16x32_bf16(a1, b1, acm, 0, 0, 0);
        acm = __builtin_amdgcn_mfma_f32_16x16x32_bf16(a2, b2, acm, 0, 0, 0);
        acm = __builtin_amdgcn_mfma_f32_16x16x32_bf16(a3, b3, acm, 0, 0, 0);
        int c0 = ct * 16 + quad * 4;
        if (onode < N) {
            out[(size_t)onode * 32 + (c0 >> 2)] =
                f32x4_to_fp8(acm[0] * di2, acm[1] * di2, acm[2] * di2, acm[3] * di2);
        }
    }
}

// ---------------- fused head: agg(fp8 quad) + b3 + relu + @Wp1+bp1 + @Wp2+bp2 + sigmoid ----------------
__global__ __launch_bounds__(256) void fhead_k(const uint2* __restrict__ hw64,
                                               const int* __restrict__ rowptr,
                                               const int* __restrict__ col,
                                               const float* __restrict__ dinv,
                                               const float* __restrict__ bias,
                                               const short* __restrict__ Wp1t,
                                               const float* __restrict__ bp1,
                                               const short* __restrict__ Wp2t,
                                               const float* __restrict__ bp2,
                                               float* __restrict__ out, int N) {
    __shared__ unsigned short rows[16][136];
    __shared__ unsigned short h1s[16][136];
    __shared__ int ldsc[4][CCAP];
    int t = threadIdx.x, wave = t >> 6, lane = t & 63;
    int q = lane >> 4, s16 = lane & 15;
    int nb0 = blockIdx.x * 16;
    int node0 = nb0 + wave * 4;
    int node = node0 + q;
    bool ok = node < N;
    int beg = rowptr[min(node0, N)];
    int e4  = rowptr[min(node0 + 4, N)];
    int begq = rowptr[min(node, N)];
    int endq = ok ? rowptr[min(node + 1, N)] : begq;
    int stagelen = min(e4 - beg, 256);
    uint2 selfd; selfd.x = 0u; selfd.y = 0u;
    float di = 0.f;
    if (ok) {
        selfd = hw64[(size_t)node * 16 + s16];
        di = dinv[node];
    }
    float acc[8] = {0.f, 0.f, 0.f, 0.f, 0.f, 0.f, 0.f, 0.f};
    gatherq(hw64, col, ldsc[wave], begq, endq, beg, stagelen, lane, s16, acc);

    float sx[8]; fp8x8_dec(selfd, sx);
    float4 bv0 = *(const float4*)(bias + 8 * s16);
    float4 bv1 = *(const float4*)(bias + 8 * s16 + 4);
    float a[8];
    a[0] = fmaxf(di * (acc[0] + sx[0]) + bv0.x, 0.f);
    a[1] = fmaxf(di * (acc[1] + sx[1]) + bv0.y, 0.f);
    a[2] = fmaxf(di * (acc[2] + sx[2]) + bv0.z, 0.f);
    a[3] = fmaxf(di * (acc[3] + sx[3]) + bv0.w, 0.f);
    a[4] = fmaxf(di * (acc[4] + sx[4]) + bv1.x, 0.f);
    a[5] = fmaxf(di * (acc[5] + sx[5]) + bv1.y, 0.f);
    a[6] = fmaxf(di * (acc[6] + sx[6]) + bv1.z, 0.f);
    a[7] = fmaxf(di * (acc[7] + sx[7]) + bv1.w, 0.f);
    if (!ok) {
#pragma unroll
        for (int k = 0; k < 8; ++k) a[k] = 0.f;
    }
    int r = wave * 4 + q;
    uint4 st;
    st.x = f2bf(a[0]) | (f2bf(a[1]) << 16);
    st.y = f2bf(a[2]) | (f2bf(a[3]) << 16);
    st.z = f2bf(a[4]) | (f2bf(a[5]) << 16);
    st.w = f2bf(a[6]) | (f2bf(a[7]) << 16);
    *(uint4*)((char*)&rows[r][0] + 16 * s16) = st;
    __syncthreads();

    int quad = lane >> 4, lr = lane & 15;
    {   // h1 = h @ Wp1 + bp1  (2 col-tiles per wave)
        short8 b0 = *(const short8*)&rows[lr][quad * 8];
        short8 b1 = *(const short8*)&rows[lr][32 + quad * 8];
        short8 b2 = *(const short8*)&rows[lr][64 + quad * 8];
        short8 b3 = *(const short8*)&rows[lr][96 + quad * 8];
#pragma unroll
        for (int k = 0; k < 2; ++k) {
            int ct = wave * 2 + k;
            int ncol = ct * 16 + lr;
            const short8* Wp = (const short8*)(Wp1t + (size_t)ncol * 128 + quad * 8);
            short8 a0 = Wp[0], a1 = Wp[4], a2 = Wp[8], a3 = Wp[12];
            floatx4 acm = {0.f, 0.f, 0.f, 0.f};
            acm = __builtin_amdgcn_mfma_f32_16x16x32_bf16(a0, b0, acm, 0, 0, 0);
            acm = __builtin_amdgcn_mfma_f32_16x16x32_bf16(a1, b1, acm, 0, 0, 0);
            acm = __builtin_amdgcn_mfma_f32_16x16x32_bf16(a2, b2, acm, 0, 0, 0);
            acm = __builtin_amdgcn_mfma_f32_16x16x32_bf16(a3, b3, acm, 0, 0, 0);
            int c0 = ct * 16 + quad * 4;
            float4 bv = *(const float4*)(bp1 + c0);
            uint2 stq;
            stq.x = f2bf(acm[0] + bv.x) | (f2bf(acm[1] + bv.y) << 16);
            stq.y = f2bf(acm[2] + bv.z) | (f2bf(acm[3] + bv.w) << 16);
            *(uint2*)&h1s[lr][c0] = stq;
        }
    }
    __syncthreads();
    {   // out = sigmoid(h1 @ Wp2 + bp2)
        short8 b0 = *(const short8*)&h1s[lr][quad * 8];
        short8 b1 = *(const short8*)&h1s[lr][32 + quad * 8];
        short8 b2 = *(const short8*)&h1s[lr][64 + quad * 8];
        short8 b3 = *(const short8*)&h1s[lr][96 + quad * 8];
        int ncol = wave * 16 + lr;
        const short8* Wp = (const short8*)(Wp2t + (size_t)ncol * 128 + quad * 8);
        short8 a0 = Wp[0], a1 = Wp[4], a2 = Wp[8], a3 = Wp[12];
        floatx4 acm = {0.f, 0.f, 0.f, 0.f};
        acm = __builtin_amdgcn_mfma_f32_16x16x32_bf16(a0, b0, acm, 0, 0, 0);
        acm = __builtin_amdgcn_mfma_f32_16x16x32_bf16(a1, b1, acm, 0, 0, 0);
        acm = __builtin_amdgcn_mfma_f32_16x16x32_bf16(a2, b2, acm, 0, 0, 0);
        acm = __builtin_amdgcn_mfma_f32_16x16x32_bf16(a3, b3, acm, 0, 0, 0);
        int c0 = wave * 16 + quad * 4;
        int onode = nb0 + lr;
        if (onode < N) {
            float4 bv = *(const float4*)(bp2 + c0);
            float4 sg;
            sg.x = 1.f / (1.f + __expf(-(acm[0] + bv.x)));
            sg.y = 1.f / (1.f + __expf(-(acm[1] + bv.y)));
            sg.z = 1.f / (1.f + __expf(-(acm[2] + bv.z)));
            sg.w = 1.f / (1.f + __expf(-(acm[3] + bv.w)));
            *(float4*)(out + (size_t)onode * 64 + c0) = sg;
        }
    }
}

extern "C" void kernel_launch(void* const* d_in, const int* in_sizes, int n_in,
                              void* d_out, int out_size, void* d_ws, size_t ws_size,
                              hipStream_t stream) {
    const int N = in_sizes[0] / 128;
    const int E = in_sizes[1] / 2;
    const int nb = (N + 255) >> 8;
    const int* edge = (const int*)d_in[1];
    const int* srcp = edge;
    const int* dstp = edge + E;
    const float* x   = (const float*)d_in[0];
    const float* W1  = (const float*)d_in[2];
    const float* b1  = (const float*)d_in[3];
    const float* W2  = (const float*)d_in[4];
    const float* b2  = (const float*)d_in[5];
    const float* W3  = (const float*)d_in[6];
    const float* b3  = (const float*)d_in[7];
    const float* g1  = (const float*)d_in[8];
    const float* be1 = (const float*)d_in[9];
    const float* g2  = (const float*)d_in[10];
    const float* be2 = (const float*)d_in[11];
    const float* Wp1 = (const float*)d_in[12];
    const float* bp1 = (const float*)d_in[13];
    const float* Wp2 = (const float*)d_in[14];
    const float* bp2 = (const float*)d_in[15];

    char* ws = (char*)d_ws;
    size_t off = 0;
    auto alloc = [&](size_t b) -> char* {
        char* p = ws + off;
        off += (b + 255) & ~(size_t)255;
        return p;
    };
    int* gcnt   = (int*)alloc(512 * 4);
    int* rowptr = (int*)alloc((size_t)(N + 1) * 4);
    float* dinv = (float*)alloc((size_t)N * 4);
    u32* pairs  = (u32*)alloc((size_t)nb * CAPB * 4);  // fixed-capacity bucket scratch
    int* colA   = (int*)alloc((size_t)E * 4);
    unsigned char* hw  = (unsigned char*)alloc((size_t)N * 128);  // fp8 rows
    unsigned char* hb  = (unsigned char*)alloc((size_t)N * 128);  // fp8 rows
    unsigned short* w1t = (unsigned short*)alloc(128 * 128 * 2);
    unsigned short* w2t = (unsigned short*)alloc(128 * 128 * 2);
    unsigned short* w3t = (unsigned short*)alloc(128 * 128 * 2);
    unsigned short* wp1t = (unsigned short*)alloc(128 * 128 * 2);
    unsigned short* wp2t = (unsigned short*)alloc(64 * 128 * 2);
    if (off > ws_size) return;

    int gb = (N + 63) / 64;
    int fb = (N + 15) / 16;
    int bucketB = (E + 8191) / 8192;

    hipMemsetAsync(gcnt, 0, 512 * 4, stream);
    bucket_trans_k<<<bucketB + 288, 256, 0, stream>>>(srcp, dstp, gcnt, pairs, E, nb,
                                                      bucketB, W1, W2, W3, Wp1, Wp2,
                                                      w1t, w2t, w3t, wp1t, wp2t);
    build_k<<<nb, 256, 0, stream>>>(pairs, gcnt, rowptr, dinv, colA, N, E, nb);

    // K1: hw = fp8((x@W1)*dinv)
    gemm1_k<<<gb, 256, 0, stream>>>(x, (const short*)w1t, dinv, (u32*)hw, N);
    // K2: hb = fp8((LN(relu(agg(hw)+b1)) @ W2)*dinv)
    fconv_k<<<fb, 256, 0, stream>>>((const uint2*)hw, rowptr, colA, dinv,
                                    b1, g1, be1, (const short*)w2t, (u32*)hb, N);
    // K3: hw = fp8((LN(relu(agg(hb)+b2)) @ W3)*dinv)
    fconv_k<<<fb, 256, 0, stream>>>((const uint2*)hb, rowptr, colA, dinv,
                                    b2, g2, be2, (const short*)w3t, (u32*)hw, N);
    // K4: out = sigmoid((relu(agg(hw)+b3) @ Wp1 + bp1) @ Wp2 + bp2)
    fhead_k<<<fb, 256, 0, stream>>>((const uint2*)hw, rowptr, colA, dinv, b3,
                                    (const short*)wp1t, bp1, (const short*)wp2t, bp2,
                                    (float*)d_out, N);
}